// Round 23
// baseline (217.704 us; speedup 1.0000x reference)
//
#include <hip/hip_runtime.h>
#include <hip/hip_bf16.h>

#define CIN 1024
#define HW2 9216
#define COUT 256
#define NSH 4
#define RHID 64
#define CPG 8
#define EPSV 1e-5f
#define GRPSZ (CPG * HW2)

typedef __attribute__((ext_vector_type(8))) short bf16x8;
typedef __attribute__((ext_vector_type(4))) float f32x4;

__device__ __forceinline__ unsigned short f2bf(float f) {
  unsigned u = __builtin_bit_cast(unsigned, f);
  u = (u + 0x7fffu + ((u >> 16) & 1u)) >> 16;
  return (unsigned short)u;
}
__device__ __forceinline__ float bf2f(unsigned short h) {
  unsigned u = (unsigned)h << 16;
  return __builtin_bit_cast(float, u);
}

// ---- kernel 1: feat -> bf16 panels + GAP partial sums ----------------------
__global__ __launch_bounds__(256) void k_prep(
    const float* __restrict__ feat, unsigned short* __restrict__ fbp,
    float* __restrict__ pooledpart) {
  __shared__ unsigned short T[512][36];
  const int seg = blockIdx.x, kq = blockIdx.y, b = blockIdx.z;
  const int tid = threadIdx.x, lane = tid & 63, w = tid >> 6;
  const int r = tid >> 3;
  const int c8 = tid & 7;
  const float* f0 = feat + ((size_t)(b * CIN + kq * 32 + r)) * HW2 + seg * 512;
  float s = 0.f;
  #pragma unroll
  for (int p = 0; p < 16; ++p) {
    int n0 = (c8 + p * 8) * 4;
    float4 v = *(const float4*)(f0 + n0);
    s += v.x + v.y + v.z + v.w;
    T[n0][r]     = f2bf(v.x);
    T[n0 + 1][r] = f2bf(v.y);
    T[n0 + 2][r] = f2bf(v.z);
    T[n0 + 3][r] = f2bf(v.w);
  }
  s += __shfl_down(s, 4); s += __shfl_down(s, 2); s += __shfl_down(s, 1);
  if (c8 == 0)
    pooledpart[((size_t)(b * CIN + kq * 32 + r)) * 18 + seg] = s;
  __syncthreads();
  unsigned short* dbase = fbp + ((size_t)(b * 32 + kq) * 576 + seg * 32) * 512;
  const int n16 = lane >> 2;
  const int cc = (lane & 3) ^ ((n16 & 3) ^ ((n16 >> 2) & 3));
  #pragma unroll
  for (int i = 0; i < 8; ++i) {
    int np = i * 4 + w;
    int n = np * 16 + n16;
    uint2 lo = *(const uint2*)&T[n][cc * 8];
    uint2 hi = *(const uint2*)&T[n][cc * 8 + 4];
    uint4 o = make_uint4(lo.x, lo.y, hi.x, hi.y);
    *(uint4*)(dbase + (size_t)np * 512 + lane * 8) = o;
  }
}

// ---- kernel 2: (18-seg reduce) + SE mlp -> s[b][4] --------------------------
__global__ __launch_bounds__(256) void k_se(
    const float* __restrict__ pooledpart, const float* __restrict__ w1,
    const float* __restrict__ b1, const float* __restrict__ w2,
    const float* __restrict__ b2, float* __restrict__ sg) {
  int b = blockIdx.x;
  __shared__ float pooled_l[1024];
  #pragma unroll
  for (int rr = 0; rr < 4; ++rr) {
    int c = rr * 256 + threadIdx.x;
    const float* p = pooledpart + ((size_t)(b * CIN + c)) * 18;
    float s = 0.f;
    #pragma unroll
    for (int i = 0; i < 18; ++i) s += p[i];
    pooled_l[c] = s;
  }
  __syncthreads();
  int r = threadIdx.x & 63, q = threadIdx.x >> 6;
  const float* pp = pooled_l + q * 256;
  const float* wrow = w1 + (size_t)r * CIN + q * 256;
  float acc = 0.f;
  for (int c = 0; c < 256; ++c) acc += pp[c] * wrow[c];
  __shared__ float part[4][64];
  __shared__ float hid[64];
  part[q][r] = acc;
  __syncthreads();
  if (q == 0) {
    float h = (part[0][r] + part[1][r] + part[2][r] + part[3][r]) *
                  (1.f / (float)HW2) + b1[r];
    hid[r] = h > 0.f ? h : 0.f;
  }
  __syncthreads();
  if (threadIdx.x < NSH) {
    float a = 0.f;
    for (int k = 0; k < RHID; ++k) a += hid[k] * w2[threadIdx.x * RHID + k];
    a += b2[threadIdx.x];
    sg[b * NSH + threadIdx.x] = 1.f / (1.f + expf(-a));
  }
}

// ---- kernel 2b: conv_weight -> bf16; also zeroes stpart --------------------
__global__ __launch_bounds__(256) void k_cw(
    const float* __restrict__ w_red, const float* __restrict__ sg,
    unsigned short* __restrict__ cw, float* __restrict__ stpart) {
  if (blockIdx.x == 0) {
    stpart[threadIdx.x] = 0.f;
    stpart[256 + threadIdx.x] = 0.f;
  }
  int e4 = (blockIdx.x * 256 + threadIdx.x) * 4;
  int b = e4 >> 18;
  int rem = e4 & 262143;
  int i = rem & 1023;
  float sv = sg[b * NSH + (i >> 8)];
  float4 v = *(const float4*)(w_red + rem);
  ushort4 o;
  o.x = f2bf(v.x * sv); o.y = f2bf(v.y * sv);
  o.z = f2bf(v.z * sv); o.w = f2bf(v.w * sv);
  *(ushort4*)(cw + e4) = o;
}

// ---- kernel 3: GEMM, depth-3 counted-vmcnt, 4 buffers = 1 barrier/step -----
// BM=128, BN=128, BK=32; 256 thr = 4 waves; LDS 64KB -> 2 blk/CU (reg cap 256).
// At step t's barrier all waves finished COMPUTE(t-1) = last reader of
// buffer (t+3)&3, so STAGE(t+3) right after the barrier needs NO 2nd barrier.
// vmcnt: 4 VMEM/STAGE/wave; steady 12 outstanding; vmcnt(8) retires stage t.
__device__ __forceinline__ void gl16(const void* g, void* l) {
  __builtin_amdgcn_global_load_lds(
      (const __attribute__((address_space(1))) unsigned int*)g,
      (__attribute__((address_space(3))) unsigned int*)l, 16, 0, 0);
}

#define WAITBAR(N)                                                        \
  asm volatile("s_waitcnt vmcnt(" #N ")\n\ts_barrier" ::: "memory");      \
  __builtin_amdgcn_sched_barrier(0);

__global__ __launch_bounds__(256, 2) void k_gemm(
    const unsigned short* __restrict__ fbp, const unsigned short* __restrict__ cw,
    unsigned short* __restrict__ xb, float* __restrict__ stpart) {
  __shared__ unsigned short A0[128 * 32];
  __shared__ unsigned short A1[128 * 32];
  __shared__ unsigned short A2[128 * 32];
  __shared__ unsigned short A3[128 * 32];
  __shared__ unsigned short B0[128 * 32];
  __shared__ unsigned short B1[128 * 32];
  __shared__ unsigned short B2[128 * 32];
  __shared__ unsigned short B3[128 * 32];
  const int wgid = blockIdx.x;
  const int b = wgid & 7;
  const int q2 = wgid >> 3;
  const int nt = q2 >> 1;          // 0..71
  const int mt = q2 & 1;           // fastest: mt-pair adjacent => B L2 hit
  const int p0 = nt * 128;
  const int tid = threadIdx.x, lane = tid & 63, w = tid >> 6;
  const int wr = w >> 1, wc = w & 1;
  const unsigned short* cwb = cw + ((size_t)b * COUT + mt * 128) * CIN;
  const unsigned short* bsrc = fbp + ((size_t)(b * 32) * 576 + nt * 8) * 512 +
                               tid * 8;
  int aoff[2];
  #pragma unroll
  for (int q = 0; q < 2; ++q) {
    int c = q * 256 + tid;
    int row = c >> 2;
    aoff[q] = row * CIN + (((c & 3) ^ ((row >> 1) & 3)) * 8);
  }

  f32x4 acc[4][4] = {};

  auto STAGE = [&](unsigned short* Ad, unsigned short* Bd, int kq) {
    #pragma unroll
    for (int q = 0; q < 2; ++q)
      gl16(cwb + aoff[q] + kq * 32, &Ad[(q * 256 + w * 64) * 8]);
    #pragma unroll
    for (int q = 0; q < 2; ++q)
      gl16(bsrc + (size_t)kq * 294912 + q * 2048, &Bd[(q * 256 + w * 64) * 8]);
  };
  auto COMPUTE = [&](const unsigned short* Ac, const unsigned short* Bc) {
    bf16x8 af[4];
    #pragma unroll
    for (int mi = 0; mi < 4; ++mi) {
      int row = wr * 64 + mi * 16 + (lane & 15);
      af[mi] = *(const bf16x8*)&Ac[row * 32 +
                                   (((lane >> 4) ^ ((row >> 1) & 3)) * 8)];
    }
    bf16x8 bfv[4];
    #pragma unroll
    for (int ni = 0; ni < 4; ++ni) {
      int n = wc * 64 + ni * 16 + (lane & 15);
      int S = (n & 3) ^ ((n >> 2) & 3);
      bfv[ni] = *(const bf16x8*)&Bc[n * 32 + (((lane >> 4) ^ S) * 8)];
    }
    #pragma unroll
    for (int mi = 0; mi < 4; ++mi)
      #pragma unroll
      for (int ni = 0; ni < 4; ++ni)
        acc[mi][ni] = __builtin_amdgcn_mfma_f32_16x16x32_bf16(
            af[mi], bfv[ni], acc[mi][ni], 0, 0, 0);
  };

  // prologue: 3 stages in flight (12 VMEM ops/wave)
  STAGE(A0, B0, 0);
  STAGE(A1, B1, 1);
  STAGE(A2, B2, 2);
  // main: t = 0..27 (7 x 4 steps); one barrier per step
  for (int it = 0; it < 7; ++it) {
    const int t = 4 * it;
    WAITBAR(8) STAGE(A3, B3, t + 3); COMPUTE(A0, B0);
    WAITBAR(8) STAGE(A0, B0, t + 4); COMPUTE(A1, B1);
    WAITBAR(8) STAGE(A1, B1, t + 5); COMPUTE(A2, B2);
    WAITBAR(8) STAGE(A2, B2, t + 6); COMPUTE(A3, B3);
  }
  // tail: t = 28..31
  WAITBAR(8) STAGE(A3, B3, 31); COMPUTE(A0, B0);   // t=28
  WAITBAR(8) COMPUTE(A1, B1);                       // t=29
  WAITBAR(4) COMPUTE(A2, B2);                       // t=30
  WAITBAR(0) COMPUTE(A3, B3);                       // t=31

  // ---- C-write (bf16): col = lane&15, row = (lane>>4)*4 + j ----
  unsigned short* ob = xb + (size_t)b * COUT * HW2;
  #pragma unroll
  for (int mi = 0; mi < 4; ++mi) {
    int r0 = mt * 128 + wr * 64 + mi * 16 + ((lane >> 4) << 2);
    #pragma unroll
    for (int ni = 0; ni < 4; ++ni) {
      int p = p0 + wc * 64 + ni * 16 + (lane & 15);
      #pragma unroll
      for (int j = 0; j < 4; ++j)
        ob[(size_t)(r0 + j) * HW2 + p] = f2bf(acc[mi][ni][j]);
    }
  }

  // ---- fused GN partial stats: g = mt*16 + wr*8 + mi*2 + (lane>=32) ----
  #pragma unroll
  for (int mi = 0; mi < 4; ++mi) {
    float s1 = 0.f, s2 = 0.f;
    #pragma unroll
    for (int ni = 0; ni < 4; ++ni)
      #pragma unroll
      for (int j = 0; j < 4; ++j) {
        float v = acc[mi][ni][j];
        s1 += v; s2 += v * v;
      }
    #pragma unroll
    for (int off = 1; off <= 16; off <<= 1) {
      s1 += __shfl_xor(s1, off);
      s2 += __shfl_xor(s2, off);
    }
    if ((lane & 31) == 0) {
      int g = mt * 16 + wr * 8 + mi * 2 + (lane >> 5);
      atomicAdd(&stpart[(b * 32 + g) * 2], s1);
      atomicAdd(&stpart[(b * 32 + g) * 2 + 1], s2);
    }
  }
}

// ---- kernel 5: GN finalize (inline) + apply + ReLU --------------------------
__global__ __launch_bounds__(256) void k_apply(
    const unsigned short* __restrict__ xb, float* __restrict__ out,
    const float* __restrict__ stpart, const float* __restrict__ gamma,
    const float* __restrict__ beta) {
  const float inv = 1.f / (float)GRPSZ;
  #pragma unroll
  for (int i = 0; i < 4; ++i) {
    unsigned e = ((unsigned)blockIdx.x * 1024 + i * 256 + threadIdx.x) * 4;
    unsigned row = (e >> 10) / 9;
    int o = row & 255;
    int bg = row >> 3;
    float mu = stpart[bg * 2] * inv;
    float rs = rsqrtf(stpart[bg * 2 + 1] * inv - mu * mu + EPSV);
    float g = gamma[o] * rs;
    float bb = beta[o] - mu * g;
    ushort4 v = *(const ushort4*)(xb + e);
    float4 r;
    r.x = fmaxf(bf2f(v.x) * g + bb, 0.f);
    r.y = fmaxf(bf2f(v.y) * g + bb, 0.f);
    r.z = fmaxf(bf2f(v.z) * g + bb, 0.f);
    r.w = fmaxf(bf2f(v.w) * g + bb, 0.f);
    *(float4*)(out + e) = r;
  }
}

extern "C" void kernel_launch(void* const* d_in, const int* in_sizes, int n_in,
                              void* d_out, int out_size, void* d_ws, size_t ws_size,
                              hipStream_t stream) {
  const float* feat  = (const float*)d_in[0];
  const float* w1    = (const float*)d_in[1];
  const float* b1    = (const float*)d_in[2];
  const float* w2    = (const float*)d_in[3];
  const float* b2    = (const float*)d_in[4];
  const float* w_red = (const float*)d_in[5];
  const float* gamma = (const float*)d_in[6];
  const float* beta  = (const float*)d_in[7];
  float* out = (float*)d_out;

  char* ws = (char*)d_ws;
  unsigned short* fbp = (unsigned short*)ws;                // 150,994,944 B
  unsigned short* cw  = (unsigned short*)(ws + 150994944);  //   4,194,304 B
  unsigned short* xbb = (unsigned short*)(ws + 155189248);  //  37,748,736 B
  float* pooledpart = (float*)(ws + 192937984);             //     589,824 B
  float* sg     = (float*)(ws + 193527808);                 //         128 B
  float* stpart = (float*)(ws + 193527936);                 //       2,048 B

  k_prep<<<dim3(18, 32, 8), 256, 0, stream>>>(feat, fbp, pooledpart);
  k_se<<<8, 256, 0, stream>>>(pooledpart, w1, b1, w2, b2, sg);
  k_cw<<<2048, 256, 0, stream>>>(w_red, sg, cw, stpart);
  k_gemm<<<1152, 256, 0, stream>>>(fbp, cw, xbb, stpart);
  k_apply<<<4608, 256, 0, stream>>>(xbb, out, stpart, gamma, beta);
}

// Round 24
// 207.886 us; speedup vs baseline: 1.0472x; 1.0472x over previous
//
#include <hip/hip_runtime.h>
#include <hip/hip_bf16.h>

#define CIN 1024
#define HW2 9216
#define COUT 256
#define NSH 4
#define RHID 64
#define CPG 8
#define EPSV 1e-5f
#define GRPSZ (CPG * HW2)

typedef __attribute__((ext_vector_type(8))) short bf16x8;
typedef __attribute__((ext_vector_type(4))) float f32x4;

__device__ __forceinline__ unsigned short f2bf(float f) {
  unsigned u = __builtin_bit_cast(unsigned, f);
  u = (u + 0x7fffu + ((u >> 16) & 1u)) >> 16;
  return (unsigned short)u;
}
__device__ __forceinline__ float bf2f(unsigned short h) {
  unsigned u = (unsigned)h << 16;
  return __builtin_bit_cast(float, u);
}

// ---- kernel 1: feat -> bf16 panels + GAP partial sums ----------------------
__global__ __launch_bounds__(256) void k_prep(
    const float* __restrict__ feat, unsigned short* __restrict__ fbp,
    float* __restrict__ pooledpart) {
  __shared__ unsigned short T[512][36];
  const int seg = blockIdx.x, kq = blockIdx.y, b = blockIdx.z;
  const int tid = threadIdx.x, lane = tid & 63, w = tid >> 6;
  const int r = tid >> 3;
  const int c8 = tid & 7;
  const float* f0 = feat + ((size_t)(b * CIN + kq * 32 + r)) * HW2 + seg * 512;
  float s = 0.f;
  #pragma unroll
  for (int p = 0; p < 16; ++p) {
    int n0 = (c8 + p * 8) * 4;
    float4 v = *(const float4*)(f0 + n0);
    s += v.x + v.y + v.z + v.w;
    T[n0][r]     = f2bf(v.x);
    T[n0 + 1][r] = f2bf(v.y);
    T[n0 + 2][r] = f2bf(v.z);
    T[n0 + 3][r] = f2bf(v.w);
  }
  s += __shfl_down(s, 4); s += __shfl_down(s, 2); s += __shfl_down(s, 1);
  if (c8 == 0)
    pooledpart[((size_t)(b * CIN + kq * 32 + r)) * 18 + seg] = s;
  __syncthreads();
  unsigned short* dbase = fbp + ((size_t)(b * 32 + kq) * 576 + seg * 32) * 512;
  const int n16 = lane >> 2;
  const int cc = (lane & 3) ^ ((n16 & 3) ^ ((n16 >> 2) & 3));
  #pragma unroll
  for (int i = 0; i < 8; ++i) {
    int np = i * 4 + w;
    int n = np * 16 + n16;
    uint2 lo = *(const uint2*)&T[n][cc * 8];
    uint2 hi = *(const uint2*)&T[n][cc * 8 + 4];
    uint4 o = make_uint4(lo.x, lo.y, hi.x, hi.y);
    *(uint4*)(dbase + (size_t)np * 512 + lane * 8) = o;
  }
}

// ---- kernel 2: (18-seg reduce) + SE mlp -> s[b][4] --------------------------
__global__ __launch_bounds__(256) void k_se(
    const float* __restrict__ pooledpart, const float* __restrict__ w1,
    const float* __restrict__ b1, const float* __restrict__ w2,
    const float* __restrict__ b2, float* __restrict__ sg) {
  int b = blockIdx.x;
  __shared__ float pooled_l[1024];
  #pragma unroll
  for (int rr = 0; rr < 4; ++rr) {
    int c = rr * 256 + threadIdx.x;
    const float* p = pooledpart + ((size_t)(b * CIN + c)) * 18;
    float s = 0.f;
    #pragma unroll
    for (int i = 0; i < 18; ++i) s += p[i];
    pooled_l[c] = s;
  }
  __syncthreads();
  int r = threadIdx.x & 63, q = threadIdx.x >> 6;
  const float* pp = pooled_l + q * 256;
  const float* wrow = w1 + (size_t)r * CIN + q * 256;
  float acc = 0.f;
  for (int c = 0; c < 256; ++c) acc += pp[c] * wrow[c];
  __shared__ float part[4][64];
  __shared__ float hid[64];
  part[q][r] = acc;
  __syncthreads();
  if (q == 0) {
    float h = (part[0][r] + part[1][r] + part[2][r] + part[3][r]) *
                  (1.f / (float)HW2) + b1[r];
    hid[r] = h > 0.f ? h : 0.f;
  }
  __syncthreads();
  if (threadIdx.x < NSH) {
    float a = 0.f;
    for (int k = 0; k < RHID; ++k) a += hid[k] * w2[threadIdx.x * RHID + k];
    a += b2[threadIdx.x];
    sg[b * NSH + threadIdx.x] = 1.f / (1.f + expf(-a));
  }
}

// ---- kernel 2b: conv_weight -> bf16; also zeroes stpart --------------------
__global__ __launch_bounds__(256) void k_cw(
    const float* __restrict__ w_red, const float* __restrict__ sg,
    unsigned short* __restrict__ cw, float* __restrict__ stpart) {
  if (blockIdx.x == 0) {
    stpart[threadIdx.x] = 0.f;
    stpart[256 + threadIdx.x] = 0.f;
  }
  int e4 = (blockIdx.x * 256 + threadIdx.x) * 4;
  int b = e4 >> 18;
  int rem = e4 & 262143;
  int i = rem & 1023;
  float sv = sg[b * NSH + (i >> 8)];
  float4 v = *(const float4*)(w_red + rem);
  ushort4 o;
  o.x = f2bf(v.x * sv); o.y = f2bf(v.y * sv);
  o.z = f2bf(v.z * sv); o.w = f2bf(v.w * sv);
  *(ushort4*)(cw + e4) = o;
}

// ---- kernel 3: GEMM, depth-3 counted-vmcnt pipeline (rule-#18 fenced) ------
// BM=128, BN=128, BK=32; 256 thr = 4 waves (2M x 2N); LDS 48KB -> 3 blk/CU.
// vmcnt ledger: 4 VMEM/STAGE/wave; steady 12 outstanding; vmcnt(8) retires
// exactly stage t. Every barrier: single asm (wait+s_barrier, "memory")
// followed by sched_barrier(0) so no MFMA/ds_read sinks past (rule #18).
__device__ __forceinline__ void gl16(const void* g, void* l) {
  __builtin_amdgcn_global_load_lds(
      (const __attribute__((address_space(1))) unsigned int*)g,
      (__attribute__((address_space(3))) unsigned int*)l, 16, 0, 0);
}

// stage-t landed (own vmcnt<=8 before barrier => all waves' stage-t landed)
#define WAITBAR(N)                                                        \
  asm volatile("s_waitcnt vmcnt(" #N ")\n\ts_barrier" ::: "memory");      \
  __builtin_amdgcn_sched_barrier(0);
// overwrite guard: all my LDS reads done (lgkmcnt 0) + barrier; pinned.
#define READBAR()                                                         \
  asm volatile("s_waitcnt lgkmcnt(0)\n\ts_barrier" ::: "memory");         \
  __builtin_amdgcn_sched_barrier(0);

__global__ __launch_bounds__(256, 3) void k_gemm(
    const unsigned short* __restrict__ fbp, const unsigned short* __restrict__ cw,
    unsigned short* __restrict__ xb, float* __restrict__ stpart) {
  __shared__ unsigned short A0[128 * 32];
  __shared__ unsigned short A1[128 * 32];
  __shared__ unsigned short A2[128 * 32];
  __shared__ unsigned short B0[128 * 32];
  __shared__ unsigned short B1[128 * 32];
  __shared__ unsigned short B2[128 * 32];
  const int wgid = blockIdx.x;
  const int b = wgid & 7;
  const int q2 = wgid >> 3;
  const int nt = q2 >> 1;          // 0..71
  const int mt = q2 & 1;           // fastest: mt-pair adjacent => B L2 hit
  const int p0 = nt * 128;
  const int tid = threadIdx.x, lane = tid & 63, w = tid >> 6;
  const int wr = w >> 1, wc = w & 1;
  const unsigned short* cwb = cw + ((size_t)b * COUT + mt * 128) * CIN;
  const unsigned short* bsrc = fbp + ((size_t)(b * 32) * 576 + nt * 8) * 512 +
                               tid * 8;
  int aoff[2];
  #pragma unroll
  for (int q = 0; q < 2; ++q) {
    int c = q * 256 + tid;
    int row = c >> 2;
    aoff[q] = row * CIN + (((c & 3) ^ ((row >> 1) & 3)) * 8);
  }

  f32x4 acc[4][4] = {};

  auto STAGE = [&](unsigned short* Ad, unsigned short* Bd, int kq) {
    #pragma unroll
    for (int q = 0; q < 2; ++q)
      gl16(cwb + aoff[q] + kq * 32, &Ad[(q * 256 + w * 64) * 8]);
    #pragma unroll
    for (int q = 0; q < 2; ++q)
      gl16(bsrc + (size_t)kq * 294912 + q * 2048, &Bd[(q * 256 + w * 64) * 8]);
  };
  auto COMPUTE = [&](const unsigned short* Ac, const unsigned short* Bc) {
    bf16x8 af[4];
    #pragma unroll
    for (int mi = 0; mi < 4; ++mi) {
      int row = wr * 64 + mi * 16 + (lane & 15);
      af[mi] = *(const bf16x8*)&Ac[row * 32 +
                                   (((lane >> 4) ^ ((row >> 1) & 3)) * 8)];
    }
    bf16x8 bfv[4];
    #pragma unroll
    for (int ni = 0; ni < 4; ++ni) {
      int n = wc * 64 + ni * 16 + (lane & 15);
      int S = (n & 3) ^ ((n >> 2) & 3);
      bfv[ni] = *(const bf16x8*)&Bc[n * 32 + (((lane >> 4) ^ S) * 8)];
    }
    #pragma unroll
    for (int mi = 0; mi < 4; ++mi)
      #pragma unroll
      for (int ni = 0; ni < 4; ++ni)
        acc[mi][ni] = __builtin_amdgcn_mfma_f32_16x16x32_bf16(
            af[mi], bfv[ni], acc[mi][ni], 0, 0, 0);
  };

  // prologue: 3 stages in flight (12 VMEM ops/wave)
  STAGE(A0, B0, 0);
  STAGE(A1, B1, 1);
  STAGE(A2, B2, 2);
  // steady state: t = 0..26
  for (int it = 0; it < 9; ++it) {
    const int t = 3 * it;
    WAITBAR(8) COMPUTE(A0, B0);
    READBAR()  STAGE(A0, B0, t + 3);
    WAITBAR(8) COMPUTE(A1, B1);
    READBAR()  STAGE(A1, B1, t + 4);
    WAITBAR(8) COMPUTE(A2, B2);
    READBAR()  STAGE(A2, B2, t + 5);
  }
  // epilogue: t = 27..31 (stages 30,31 issued at t=27,28)
  WAITBAR(8) COMPUTE(A0, B0);          // t=27
  READBAR()  STAGE(A0, B0, 30);
  WAITBAR(8) COMPUTE(A1, B1);          // t=28
  READBAR()  STAGE(A1, B1, 31);
  WAITBAR(8) COMPUTE(A2, B2);          // t=29
  WAITBAR(4) COMPUTE(A0, B0);          // t=30
  WAITBAR(0) COMPUTE(A1, B1);          // t=31

  // ---- C-write (bf16): col = lane&15, row = (lane>>4)*4 + j ----
  unsigned short* ob = xb + (size_t)b * COUT * HW2;
  #pragma unroll
  for (int mi = 0; mi < 4; ++mi) {
    int r0 = mt * 128 + wr * 64 + mi * 16 + ((lane >> 4) << 2);
    #pragma unroll
    for (int ni = 0; ni < 4; ++ni) {
      int p = p0 + wc * 64 + ni * 16 + (lane & 15);
      #pragma unroll
      for (int j = 0; j < 4; ++j)
        ob[(size_t)(r0 + j) * HW2 + p] = f2bf(acc[mi][ni][j]);
    }
  }

  // ---- fused GN partial stats: g = mt*16 + wr*8 + mi*2 + (lane>=32) ----
  #pragma unroll
  for (int mi = 0; mi < 4; ++mi) {
    float s1 = 0.f, s2 = 0.f;
    #pragma unroll
    for (int ni = 0; ni < 4; ++ni)
      #pragma unroll
      for (int j = 0; j < 4; ++j) {
        float v = acc[mi][ni][j];
        s1 += v; s2 += v * v;
      }
    #pragma unroll
    for (int off = 1; off <= 16; off <<= 1) {
      s1 += __shfl_xor(s1, off);
      s2 += __shfl_xor(s2, off);
    }
    if ((lane & 31) == 0) {
      int g = mt * 16 + wr * 8 + mi * 2 + (lane >> 5);
      atomicAdd(&stpart[(b * 32 + g) * 2], s1);
      atomicAdd(&stpart[(b * 32 + g) * 2 + 1], s2);
    }
  }
}

// ---- kernel 5: GN finalize (inline) + apply + ReLU --------------------------
__global__ __launch_bounds__(256) void k_apply(
    const unsigned short* __restrict__ xb, float* __restrict__ out,
    const float* __restrict__ stpart, const float* __restrict__ gamma,
    const float* __restrict__ beta) {
  const float inv = 1.f / (float)GRPSZ;
  #pragma unroll
  for (int i = 0; i < 4; ++i) {
    unsigned e = ((unsigned)blockIdx.x * 1024 + i * 256 + threadIdx.x) * 4;
    unsigned row = (e >> 10) / 9;
    int o = row & 255;
    int bg = row >> 3;
    float mu = stpart[bg * 2] * inv;
    float rs = rsqrtf(stpart[bg * 2 + 1] * inv - mu * mu + EPSV);
    float g = gamma[o] * rs;
    float bb = beta[o] - mu * g;
    ushort4 v = *(const ushort4*)(xb + e);
    float4 r;
    r.x = fmaxf(bf2f(v.x) * g + bb, 0.f);
    r.y = fmaxf(bf2f(v.y) * g + bb, 0.f);
    r.z = fmaxf(bf2f(v.z) * g + bb, 0.f);
    r.w = fmaxf(bf2f(v.w) * g + bb, 0.f);
    *(float4*)(out + e) = r;
  }
}

extern "C" void kernel_launch(void* const* d_in, const int* in_sizes, int n_in,
                              void* d_out, int out_size, void* d_ws, size_t ws_size,
                              hipStream_t stream) {
  const float* feat  = (const float*)d_in[0];
  const float* w1    = (const float*)d_in[1];
  const float* b1    = (const float*)d_in[2];
  const float* w2    = (const float*)d_in[3];
  const float* b2    = (const float*)d_in[4];
  const float* w_red = (const float*)d_in[5];
  const float* gamma = (const float*)d_in[6];
  const float* beta  = (const float*)d_in[7];
  float* out = (float*)d_out;

  char* ws = (char*)d_ws;
  unsigned short* fbp = (unsigned short*)ws;                // 150,994,944 B
  unsigned short* cw  = (unsigned short*)(ws + 150994944);  //   4,194,304 B
  unsigned short* xbb = (unsigned short*)(ws + 155189248);  //  37,748,736 B
  float* pooledpart = (float*)(ws + 192937984);             //     589,824 B
  float* sg     = (float*)(ws + 193527808);                 //         128 B
  float* stpart = (float*)(ws + 193527936);                 //       2,048 B

  k_prep<<<dim3(18, 32, 8), 256, 0, stream>>>(feat, fbp, pooledpart);
  k_se<<<8, 256, 0, stream>>>(pooledpart, w1, b1, w2, b2, sg);
  k_cw<<<2048, 256, 0, stream>>>(w_red, sg, cw, stpart);
  k_gemm<<<1152, 256, 0, stream>>>(fbp, cw, xbb, stpart);
  k_apply<<<4608, 256, 0, stream>>>(xbb, out, stpart, gamma, beta);
}